// Round 15
// baseline (345.187 us; speedup 1.0000x reference)
//
#include <hip/hip_runtime.h>
#include <math.h>

#define N_ROWS 16384
#define VOCAB  8192
#define EMB    256

// ---- MFMA path tiling ----
#define BM 128
#define BV 128
#define BK 64                      // halfs per staged cb K-chunk (2 MFMA k-steps)
#define VSPLIT 8                   // grid (128, 8)
#define VRANGE (VOCAB / VSPLIT)    // 1024
#define NVT    (VRANGE / BV)       // 8
#define TAU  0.15f                 // top-3 window: 2*max approx err (E<=0.075)
#define ETAU 1e-3f                 // exact-rerank tie guard (fp32 rounding-order)

typedef _Float16 half8 __attribute__((ext_vector_type(8)));
typedef _Float16 half4 __attribute__((ext_vector_type(4)));
typedef float floatx4 __attribute__((ext_vector_type(4)));

// async global->LDS DMA, 16 B/lane; LDS dest = wave-uniform base + lane*16
__device__ __forceinline__ void load_lds16(const _Float16* g, _Float16* l) {
    __builtin_amdgcn_global_load_lds(
        (const __attribute__((address_space(1))) void*)g,
        (__attribute__((address_space(3))) void*)l, 16, 0, 0);
}

// ---------------------------------------------------------------------------
// PREP (1 dispatch: esq + fp16 convert + output/scratch init).
// ---------------------------------------------------------------------------
__global__ void prep_kernel(const float* __restrict__ z, const float* __restrict__ cb,
                            _Float16* __restrict__ zh, _Float16* __restrict__ ch,
                            float* __restrict__ esq, float* __restrict__ cnt,
                            unsigned long long* __restrict__ rkey,
                            int* __restrict__ flagcnt) {
    const int b = blockIdx.x, t = threadIdx.x;
    if (b < VOCAB / 4) {
        const int row  = b * 4 + (t >> 6);
        const int lane = t & 63;
        const float4 f = *(const float4*)(cb + (size_t)row * EMB + lane * 4);
        half4 h;
        h.x = (_Float16)f.x; h.y = (_Float16)f.y; h.z = (_Float16)f.z; h.w = (_Float16)f.w;
        *(half4*)(ch + (size_t)row * EMB + lane * 4) = h;
        float s = f.x * f.x + f.y * f.y + f.z * f.z + f.w * f.w;
        #pragma unroll
        for (int off = 32; off > 0; off >>= 1) s += __shfl_down(s, off, 64);
        if (lane == 0) esq[row] = s;
        if (t < 4) cnt[b * 4 + t] = 0.0f;
        if (t >= 8 && t < 16) rkey[b * 8 + (t - 8)] = ~0ull;
        if (b == 0 && t == 4) *flagcnt = 0;
    } else {
        const size_t idx4 = (size_t)(b - VOCAB / 4) * 256 + t;
        const float4 f = *(const float4*)(z + idx4 * 4);
        half4 h;
        h.x = (_Float16)f.x; h.y = (_Float16)f.y; h.z = (_Float16)f.z; h.w = (_Float16)f.w;
        *(half4*)(zh + idx4 * 4) = h;
    }
}

// ---------------------------------------------------------------------------
// MFMA dist kernel v10 = v9 (z-resident LDS + swizzles) + TOP-3 tracking.
// Rounds 9-14 post-mortem: top-2 margin test flags ~870 rows (rescue-bound);
// true argmin is outside approx top-2 only if d3-d1 < 2E -> top-3 window
// shrinks flags to ~2. acc = z.e - esq/2; per-row arg-TOP-3 of acc.
// ---------------------------------------------------------------------------
__global__ __launch_bounds__(256, 2)
void mfma_dist_kernel(const _Float16* __restrict__ zh, const _Float16* __restrict__ ch,
                      const float* __restrict__ esq,
                      float* __restrict__ pd1, int* __restrict__ pi1,
                      float* __restrict__ pd2, int* __restrict__ pi2,
                      float* __restrict__ pd3) {
    __shared__ _Float16 zl[BM * 256];  // 64 KB, resident z tile (swizzled)
    __shared__ _Float16 cs[BV * BK];   // 16 KB, per-kt cb tile
    // end-phase scratch aliases zl (5 KB; z dead by then)
    float* sc_m1 = (float*)zl;
    float* sc_m2 = sc_m1 + BM * 2;
    float* sc_m3 = sc_m2 + BM * 2;
    int*   sc_i1 = (int*)(sc_m3 + BM * 2);
    int*   sc_i2 = sc_i1 + BM * 2;

    const int row0  = blockIdx.x * BM;
    const int vbase = blockIdx.y * VRANGE;

    const int tid  = threadIdx.x;
    const int w    = tid >> 6;
    const int lane = tid & 63;
    const int lr   = lane & 15;
    const int quad = lane >> 4;
    const int mh   = (w >> 1) * 64;
    const int vh   = (w & 1) * 64;

    // ---- stage z ONCE (swizzled slot = c ^ (r&31)) ----
    {
        const int rl = lane >> 5;
        const int sc = lane & 31;
        #pragma unroll
        for (int i = 0; i < 16; ++i) {
            const int r = w * 32 + i * 2 + rl;
            const int c = sc ^ (i * 2 + rl);
            load_lds16(zh + (size_t)(row0 + r) * EMB + c * 8,
                       zl + (size_t)(w * 1024 + i * 64) * 8);
        }
    }

    int rowOffZ[4];
    #pragma unroll
    for (int i = 0; i < 4; ++i) rowOffZ[i] = (mh + i * 16 + lr) * 256;

    const int q7 = quad ^ (lr & 7);
    const int offA0 = q7 * 8;
    const int offA1 = (4 ^ q7) * 8;
    int rB[4];
    #pragma unroll
    for (int j = 0; j < 4; ++j) rB[j] = (vh + j * 16 + lr) * BK;

    const int schunk = (lane & 7) ^ (lane >> 3);

    // per-lane top-3 (argmax over acc) + indices of top-2
    float m1[16], m2[16], m3[16]; int i1[16], i2[16];
    #pragma unroll
    for (int t = 0; t < 16; ++t) {
        m1[t] = -INFINITY; m2[t] = -INFINITY; m3[t] = -INFINITY;
        i1[t] = 0; i2[t] = 0;
    }

    float ev[4];
    #pragma unroll
    for (int j = 0; j < 4; ++j) ev[j] = esq[vbase + vh + j * 16 + lr];

    __syncthreads();   // z DMA drained

    for (int vt = 0; vt < NVT; ++vt) {
        const int v0 = vbase + vt * BV;
        const _Float16* csrc = ch + (size_t)(v0 + w * 32 + (lane >> 3)) * EMB + schunk * 8;

        floatx4 acc[4][4];
        #pragma unroll
        for (int j = 0; j < 4; ++j) {
            const float e2 = -0.5f * ev[j];
            #pragma unroll
            for (int i = 0; i < 4; ++i) acc[i][j] = (floatx4)e2;
        }
        float evn[4];
        {
            const int vtn = (vt + 1 < NVT) ? vt + 1 : vt;
            #pragma unroll
            for (int j = 0; j < 4; ++j) evn[j] = esq[vbase + vtn * BV + vh + j * 16 + lr];
        }

        #pragma unroll 1
        for (int kt = 0; kt < EMB / BK; ++kt) {
            const int ko = kt * BK;
            #pragma unroll
            for (int q = 0; q < 4; ++q)
                load_lds16(csrc + (size_t)q * 8 * EMB + ko, &cs[w * 2048 + q * 512]);
            __syncthreads();

            #pragma unroll
            for (int s = 0; s < 2; ++s) {
                const int ks = kt * 2 + s;
                const int cE = (((ks << 2) | quad) ^ lr) << 3;
                const int cO = cE ^ 128;
                half8 a[4];
                a[0] = *(const half8*)&zl[rowOffZ[0] + cE];
                a[1] = *(const half8*)&zl[rowOffZ[1] + cO];
                a[2] = *(const half8*)&zl[rowOffZ[2] + cE];
                a[3] = *(const half8*)&zl[rowOffZ[3] + cO];
                const int off = s ? offA1 : offA0;
                #pragma unroll
                for (int j = 0; j < 4; ++j) {
                    const half8 b = *(const half8*)&cs[rB[j] + off];
                    #pragma unroll
                    for (int i = 0; i < 4; ++i)
                        acc[i][j] = __builtin_amdgcn_mfma_f32_16x16x32_f16(a[i], b, acc[i][j], 0, 0, 0);
                }
            }
            __syncthreads();
        }

        // epilogue: per-lane top-3 pushes (register-only)
        int vj[4];
        #pragma unroll
        for (int j = 0; j < 4; ++j) vj[j] = v0 + vh + j * 16 + lr;
        #pragma unroll
        for (int i = 0; i < 4; ++i) {
            #pragma unroll
            for (int reg = 0; reg < 4; ++reg) {
                const int t = i * 4 + reg;
                #pragma unroll
                for (int j = 0; j < 4; ++j) {
                    const float a = acc[i][j][reg];
                    const int   v = vj[j];
                    if (a > m1[t]) { m3[t] = m2[t]; m2[t] = m1[t]; i2[t] = i1[t]; m1[t] = a; i1[t] = v; }
                    else if (a > m2[t]) { m3[t] = m2[t]; m2[t] = a; i2[t] = v; }
                    else m3[t] = fmaxf(m3[t], a);
                }
            }
        }
        #pragma unroll
        for (int j = 0; j < 4; ++j) ev[j] = evn[j];
    }

    // cross-lane top-3 merge: 16 lr-lanes share each row. Scoped pushes:
    // o1 can enter slot1; o2 only slot2/3 (o2<=o1<=new a1); o3 only slot3.
    #pragma unroll
    for (int t = 0; t < 16; ++t) {
        float a1 = m1[t], a2 = m2[t], a3 = m3[t]; int b1 = i1[t], b2 = i2[t];
        #pragma unroll
        for (int off = 1; off < 16; off <<= 1) {
            const float o1 = __shfl_xor(a1, off, 64);
            const float o2 = __shfl_xor(a2, off, 64);
            const float o3 = __shfl_xor(a3, off, 64);
            const int  oi1 = __shfl_xor(b1, off, 64);
            const int  oi2 = __shfl_xor(b2, off, 64);
            if (o1 > a1) { a3 = a2; a2 = a1; b2 = b1; a1 = o1; b1 = oi1; }
            else if (o1 > a2) { a3 = a2; a2 = o1; b2 = oi1; }
            else a3 = fmaxf(a3, o1);
            if (o2 > a2) { a3 = a2; a2 = o2; b2 = oi2; }
            else a3 = fmaxf(a3, o2);
            a3 = fmaxf(a3, o3);
        }
        m1[t] = a1; m2[t] = a2; m3[t] = a3; i1[t] = b1; i2[t] = b2;
    }
    // all waves past last kt barrier -> zl alias safe
    if (lr == 0) {
        #pragma unroll
        for (int t = 0; t < 16; ++t) {
            const int r = mh + (t >> 2) * 16 + quad * 4 + (t & 3);
            sc_m1[r * 2 + (w & 1)] = m1[t];
            sc_m2[r * 2 + (w & 1)] = m2[t];
            sc_m3[r * 2 + (w & 1)] = m3[t];
            sc_i1[r * 2 + (w & 1)] = i1[t];
            sc_i2[r * 2 + (w & 1)] = i2[t];
        }
    }
    __syncthreads();
    if (tid < BM) {
        float a1 = sc_m1[tid * 2], a2 = sc_m2[tid * 2], a3 = sc_m3[tid * 2];
        int b1 = sc_i1[tid * 2], b2 = sc_i2[tid * 2];
        const float o1 = sc_m1[tid * 2 + 1], o2 = sc_m2[tid * 2 + 1], o3 = sc_m3[tid * 2 + 1];
        const int oi1 = sc_i1[tid * 2 + 1], oi2 = sc_i2[tid * 2 + 1];
        if (o1 > a1) { a3 = a2; a2 = a1; b2 = b1; a1 = o1; b1 = oi1; }
        else if (o1 > a2) { a3 = a2; a2 = o1; b2 = oi1; }
        else a3 = fmaxf(a3, o1);
        if (o2 > a2) { a3 = a2; a2 = o2; b2 = oi2; }
        else a3 = fmaxf(a3, o2);
        a3 = fmaxf(a3, o3);
        const size_t o = (size_t)blockIdx.y * N_ROWS + row0 + tid;
        pd1[o] = -2.0f * a1; pi1[o] = b1;      // dist ascending
        pd2[o] = -2.0f * a2; pi2[o] = b2;
        pd3[o] = -2.0f * a3;
    }
}

// ---------------------------------------------------------------------------
// Combine v2: merge VSPLIT top-3 partials; EXACT fp32 re-rank of top-2
// (wave-parallel dots, codebook rows reused for zq); flag only if the
// top-3 window is ambiguous (d3-d1 < TAU) or exact margins tie (< ETAU).
// ---------------------------------------------------------------------------
__global__ void combine_kernel(const float* __restrict__ pd1, const int* __restrict__ pi1,
                               const float* __restrict__ pd2, const int* __restrict__ pi2,
                               const float* __restrict__ pd3,
                               const float* __restrict__ z, const float* __restrict__ cb,
                               const float* __restrict__ esq,
                               float* __restrict__ tokens, float* __restrict__ zq,
                               float* __restrict__ cnt,
                               int* __restrict__ flagcnt, int* __restrict__ flaglist) {
    const int wave = threadIdx.x >> 6;
    const int lane = threadIdx.x & 63;
    const int row  = blockIdx.x * 4 + wave;

    float d1 = pd1[row], d2 = pd2[row], d3 = pd3[row];
    int   i1 = pi1[row], i2 = pi2[row];
    #pragma unroll
    for (int s = 1; s < VSPLIT; ++s) {
        const size_t o = (size_t)s * N_ROWS + row;
        const float o1 = pd1[o], o2 = pd2[o], o3 = pd3[o];
        const int oi1 = pi1[o], oi2 = pi2[o];
        if (o1 < d1) { d3 = d2; d2 = d1; i2 = i1; d1 = o1; i1 = oi1; }
        else if (o1 < d2) { d3 = d2; d2 = o1; i2 = oi1; }
        else d3 = fminf(d3, o1);
        if (o2 < d2) { d3 = d2; d2 = o2; i2 = oi2; }
        else d3 = fminf(d3, o2);
        d3 = fminf(d3, o3);
    }

    // exact fp32 dots for the two approx-best codes
    const float4 z4 = *(const float4*)(z + (size_t)row * EMB + lane * 4);
    const float4 c1 = *(const float4*)(cb + (size_t)i1 * EMB + lane * 4);
    const float4 c2 = *(const float4*)(cb + (size_t)i2 * EMB + lane * 4);
    float p1 = z4.x * c1.x + z4.y * c1.y + z4.z * c1.z + z4.w * c1.w;
    float p2 = z4.x * c2.x + z4.y * c2.y + z4.z * c2.z + z4.w * c2.w;
    #pragma unroll
    for (int off = 1; off < 64; off <<= 1) {
        p1 += __shfl_xor(p1, off, 64);
        p2 += __shfl_xor(p2, off, 64);
    }
    const float e1 = esq[i1] - 2.0f * p1;
    const float e2 = esq[i2] - 2.0f * p2;

    if ((d3 - d1 < TAU) || (fabsf(e1 - e2) < ETAU)) {
        if (lane == 0) {
            const int pos = atomicAdd(flagcnt, 1);
            flaglist[pos] = row;
        }
        return;   // exact rescue writes this row
    }
    const bool second = (e2 < e1) || (e2 == e1 && i2 < i1);
    const int win = second ? i2 : i1;
    if (lane == 0) {
        tokens[row] = (float)win;
        atomicAdd(&cnt[win], 1.0f);
    }
    const float4 c4 = second ? c2 : c1;
    *(float4*)(zq + (size_t)row * EMB + lane * 4) = c4;
}

// ---------------------------------------------------------------------------
// Rescue (round-10 rescue4, 60 VGPR no-spill): exact fp32 argmin over all
// codes for flagged rows. With top-3 combine, n ~ 2-4 -> a few us.
// ---------------------------------------------------------------------------
__global__ void rescue4_kernel(const int* __restrict__ flagcnt, const int* __restrict__ flaglist,
                               const float* __restrict__ z, const float* __restrict__ cb,
                               const float* __restrict__ esq,
                               unsigned long long* __restrict__ rkey) {
    const int tid  = threadIdx.x;
    const int w    = tid >> 6;
    const int lane = tid & 63;
    const int g    = lane >> 2;
    const int s    = lane & 3;
    const int n = *flagcnt;
    const int waveId = blockIdx.x * 4 + w;
    const int nwaves = gridDim.x * 4;
    const int njobs  = n * 128;        // 128 chunks of 64 codes per row
    for (int j = waveId; j < njobs; j += nwaves) {
        const int row = flaglist[j >> 7];
        const int c0  = (j & 127) * 64;
        const float* zr = z + (size_t)row * EMB;
        float p[4] = {0.0f, 0.0f, 0.0f, 0.0f};
        #pragma unroll
        for (int kb = 0; kb < 4; ++kb) {
            float4 zv[4];
            #pragma unroll
            for (int kk = 0; kk < 4; ++kk)
                zv[kk] = *(const float4*)(zr + (kb * 4 + kk) * 16 + s * 4);
            #pragma unroll
            for (int gs = 0; gs < 4; ++gs) {
                const float* cr = cb + (size_t)(c0 + gs * 16 + g) * EMB;
                #pragma unroll
                for (int kk = 0; kk < 4; ++kk) {
                    const float4 c4 = *(const float4*)(cr + (kb * 4 + kk) * 16 + s * 4);
                    p[gs] += zv[kk].x * c4.x + zv[kk].y * c4.y
                           + zv[kk].z * c4.z + zv[kk].w * c4.w;
                }
            }
        }
        float bd = INFINITY; int bv = 0;
        #pragma unroll
        for (int gs = 0; gs < 4; ++gs) {
            float pp = p[gs];
            pp += __shfl_xor(pp, 1, 64);
            pp += __shfl_xor(pp, 2, 64);
            const int v = c0 + gs * 16 + g;
            const float d = esq[v] - 2.0f * pp;
            if (d < bd) { bd = d; bv = v; }
        }
        #pragma unroll
        for (int off = 4; off < 64; off <<= 1) {
            const float od = __shfl_xor(bd, off, 64);
            const int   ov = __shfl_xor(bv, off, 64);
            if (od < bd || (od == bd && ov < bv)) { bd = od; bv = ov; }
        }
        if (lane == 0) {
            unsigned int u = __float_as_uint(bd);
            u = (u & 0x80000000u) ? ~u : (u | 0x80000000u);
            atomicMin(rkey + row, ((unsigned long long)u << 32) | (unsigned int)bv);
        }
    }
}

// ---------------------------------------------------------------------------
// Rescue writer: separate dispatch (kernel boundary = visibility ordering).
// ---------------------------------------------------------------------------
__global__ void rescue_write_kernel(const int* __restrict__ flagcnt,
                                    const int* __restrict__ flaglist,
                                    const unsigned long long* __restrict__ rkey,
                                    const float* __restrict__ cb,
                                    float* __restrict__ tokens, float* __restrict__ zq,
                                    float* __restrict__ cnt) {
    const int w    = threadIdx.x >> 6;
    const int lane = threadIdx.x & 63;
    const int n = *flagcnt;
    for (int f = blockIdx.x * 4 + w; f < n; f += gridDim.x * 4) {
        const int row = flaglist[f];
        const int v = (int)(unsigned int)(rkey[row] & 0xFFFFFFFFull);
        if (lane == 0) {
            tokens[row] = (float)v;
            atomicAdd(&cnt[v], 1.0f);
        }
        const float4 c4 = *(const float4*)(cb + (size_t)v * EMB + lane * 4);
        *(float4*)(zq + (size_t)row * EMB + lane * 4) = c4;
    }
}

// ===========================================================================
// Fallback (round-3 fp32 path) if ws is too small.
// ===========================================================================
__global__ void esq_kernel(const float* __restrict__ cb, float* __restrict__ esq) {
    const int wave = threadIdx.x >> 6;
    const int lane = threadIdx.x & 63;
    const int row  = blockIdx.x * 4 + wave;
    const float4 v = *(const float4*)(cb + (size_t)row * EMB + lane * 4);
    float s = v.x * v.x + v.y * v.y + v.z * v.z + v.w * v.w;
    #pragma unroll
    for (int off = 32; off > 0; off >>= 1) s += __shfl_down(s, off, 64);
    if (lane == 0) esq[row] = s;
}

#define FLSTR 36
__global__ __launch_bounds__(256, 2)
void fb_dist_kernel(const float* __restrict__ z, const float* __restrict__ cb,
                    const float* __restrict__ esq,
                    float* __restrict__ pdist, int* __restrict__ pidx) {
    __shared__ float zs[BM][FLSTR];
    __shared__ float es[BV][FLSTR];
    __shared__ float rdist[16][16];
    __shared__ int   ridx [16][16];
    const int row0 = blockIdx.x * BM, vbase = blockIdx.y * VRANGE;
    const int tid = threadIdx.x, wave = tid >> 6, lane = tid & 63;
    const int wly = (lane >> 3) & 7, wlx = lane & 7;
    const int wbase = (wave >> 1) * 64, cbase = (wave & 1) * 64;
    const int arow = wbase + wly, bcol = cbase + wlx;
    const int rowSlot = (wave >> 1) * 8 + wly, colSlot = (wave & 1) * 8 + wlx;
    const int sc4 = tid & 7, sr0 = tid >> 3;
    float best[8]; int bidx[8];
    #pragma unroll
    for (int i = 0; i < 8; ++i) { best[i] = INFINITY; bidx[i] = 0; }
    for (int vt = 0; vt < NVT; ++vt) {
        const int v0 = vbase + vt * BV;
        float acc[8][8];
        #pragma unroll
        for (int i = 0; i < 8; ++i)
            #pragma unroll
            for (int j = 0; j < 8; ++j) acc[i][j] = 0.0f;
        #pragma unroll 1
        for (int kt = 0; kt < EMB / 32; ++kt) {
            #pragma unroll
            for (int t = 0; t < 4; ++t) {
                const int r = sr0 + 32 * t;
                *(float4*)&zs[r][sc4 * 4] = *(const float4*)(z  + (size_t)(row0 + r) * EMB + kt * 32 + sc4 * 4);
                *(float4*)&es[r][sc4 * 4] = *(const float4*)(cb + (size_t)(v0 + r) * EMB + kt * 32 + sc4 * 4);
            }
            __syncthreads();
            #pragma unroll 1
            for (int k0 = 0; k0 < 8; ++k0) {
                const int kk = k0 * 4;
                float a[8][4];
                #pragma unroll
                for (int i = 0; i < 8; ++i) {
                    const float4 a4 = *(const float4*)&zs[arow + 8 * i][kk];
                    a[i][0] = a4.x; a[i][1] = a4.y; a[i][2] = a4.z; a[i][3] = a4.w;
                }
                #pragma unroll
                for (int j = 0; j < 8; ++j) {
                    const float4 b4 = *(const float4*)&es[bcol + 8 * j][kk];
                    #pragma unroll
                    for (int i = 0; i < 8; ++i) {
                        acc[i][j] += a[i][0] * b4.x; acc[i][j] += a[i][1] * b4.y;
                        acc[i][j] += a[i][2] * b4.z; acc[i][j] += a[i][3] * b4.w;
                    }
                }
            }
            __syncthreads();
        }
        #pragma unroll
        for (int j = 0; j < 8; ++j) {
            const int v = v0 + bcol + 8 * j;
            const float evv = esq[v];
            #pragma unroll
            for (int i = 0; i < 8; ++i) {
                const float d = evv - 2.0f * acc[i][j];
                if (d < best[i]) { best[i] = d; bidx[i] = v; }
            }
        }
    }
    for (int i = 0; i < 8; ++i) {
        rdist[rowSlot][colSlot] = best[i];
        ridx [rowSlot][colSlot] = bidx[i];
        __syncthreads();
        if (colSlot == 0) {
            float bd = rdist[rowSlot][0]; int bi = ridx[rowSlot][0];
            #pragma unroll
            for (int t = 1; t < 16; ++t) {
                const float d = rdist[rowSlot][t]; const int ii = ridx[rowSlot][t];
                if (d < bd || (d == bd && ii < bi)) { bd = d; bi = ii; }
            }
            const int row = row0 + wbase + 8 * i + wly;
            pdist[(size_t)blockIdx.y * N_ROWS + row] = bd;
            pidx [(size_t)blockIdx.y * N_ROWS + row] = bi;
        }
        __syncthreads();
    }
}

__global__ void fb_combine_kernel(const float* __restrict__ pdist, const int* __restrict__ pidx,
                                  const float* __restrict__ cb,
                                  float* __restrict__ tokens, float* __restrict__ zq,
                                  float* __restrict__ cnt) {
    const int wave = threadIdx.x >> 6, lane = threadIdx.x & 63;
    const int row = blockIdx.x * 4 + wave;
    float bd = INFINITY; int bi = 0;
    #pragma unroll
    for (int s = 0; s < VSPLIT; ++s) {
        const float d = pdist[(size_t)s * N_ROWS + row];
        const int ii  = pidx [(size_t)s * N_ROWS + row];
        if (d < bd || (d == bd && ii < bi)) { bd = d; bi = ii; }
    }
    if (lane == 0) { tokens[row] = (float)bi; atomicAdd(&cnt[bi], 1.0f); }
    const float4 v = *(const float4*)(cb + (size_t)bi * EMB + lane * 4);
    *(float4*)(zq + (size_t)row * EMB + lane * 4) = v;
}

// ---------------------------------------------------------------------------
// d_out: [0,N) tokens | [N, N+N*EMB) zq | +VOCAB ref_count
// ws: zh | ch | esq | pd1|pd2|pd3|pi1|pi2 | rkey | flagcnt | flaglist ~15 MB
// 5 dispatches: prep -> mfma_dist -> combine -> rescue4 -> rescue_write
// ---------------------------------------------------------------------------
extern "C" void kernel_launch(void* const* d_in, const int* in_sizes, int n_in,
                              void* d_out, int out_size, void* d_ws, size_t ws_size,
                              hipStream_t stream) {
    const float* z  = (const float*)d_in[0];
    const float* cb = (const float*)d_in[1];

    float* out    = (float*)d_out;
    float* tokens = out;
    float* zq     = out + N_ROWS;
    float* cnt    = out + N_ROWS + (size_t)N_ROWS * EMB;

    const size_t ZE = (size_t)N_ROWS * EMB, CE = (size_t)VOCAB * EMB, P = (size_t)VSPLIT * N_ROWS;
    const size_t NEED = (ZE + CE) * sizeof(_Float16) + VOCAB * 4
                      + 5 * P * 4 + (size_t)N_ROWS * 8 + 256 + N_ROWS * 4;

    if (ws_size >= NEED) {
        char* p = (char*)d_ws;
        _Float16* zh = (_Float16*)p;            p += ZE * 2;
        _Float16* ch = (_Float16*)p;            p += CE * 2;
        float* esq   = (float*)p;               p += VOCAB * 4;
        float* pd1   = (float*)p;               p += P * 4;
        float* pd2   = (float*)p;               p += P * 4;
        float* pd3   = (float*)p;               p += P * 4;
        int*   pi1   = (int*)p;                 p += P * 4;
        int*   pi2   = (int*)p;                 p += P * 4;
        unsigned long long* rkey = (unsigned long long*)p;  p += (size_t)N_ROWS * 8;
        int*   flagcnt = (int*)p;               p += 256;
        int*   flaglist = (int*)p;

        prep_kernel<<<VOCAB / 4 + (int)(ZE / 4 / 256), 256, 0, stream>>>(
            z, cb, zh, ch, esq, cnt, rkey, flagcnt);
        mfma_dist_kernel<<<dim3(N_ROWS / BM, VSPLIT), 256, 0, stream>>>(
            zh, ch, esq, pd1, pi1, pd2, pi2, pd3);
        combine_kernel<<<N_ROWS / 4, 256, 0, stream>>>(
            pd1, pi1, pd2, pi2, pd3, z, cb, esq, tokens, zq, cnt, flagcnt, flaglist);
        rescue4_kernel<<<2048, 256, 0, stream>>>(flagcnt, flaglist, z, cb, esq, rkey);
        rescue_write_kernel<<<32, 256, 0, stream>>>(flagcnt, flaglist, rkey, cb, tokens, zq, cnt);
    } else {
        float* esq   = (float*)d_ws;
        float* pdist = esq + VOCAB;
        int*   pidx  = (int*)(pdist + P);
        hipMemsetAsync(cnt, 0, VOCAB * sizeof(float), stream);
        esq_kernel<<<VOCAB / 4, 256, 0, stream>>>(cb, esq);
        fb_dist_kernel<<<dim3(N_ROWS / BM, VSPLIT), 256, 0, stream>>>(z, cb, esq, pdist, pidx);
        fb_combine_kernel<<<N_ROWS / 4, 256, 0, stream>>>(pdist, pidx, cb, tokens, zq, cnt);
    }
}